// Round 7
// baseline (945.035 us; speedup 1.0000x reference)
//
#include <hip/hip_runtime.h>
#include <hip/hip_bf16.h>

#define N 512
#define CS 1024
#define CZ 128
#define H 12
#define HD 16

// All inputs are float32 (reference is jnp.float32; confirmed by R2 counters:
// final WRITE_SIZE=2048KB = 512*1024*4B). Output is float32.

// ---------------------------------------------------------------------------
// K1: unified projection GEMM + point rotation. grid 256 blocks (2 rows each)
// x 288 threads (4 cols each of the 1152-col concat [q192|kv384|qp144|kvp432]).
// float4 weight loads; s rows staged in LDS.
// ---------------------------------------------------------------------------
__global__ void proj_all(const float* s, const float* Wq, const float* bq,
                         const float* Wkv, const float* bkv,
                         const float* Wqp, const float* bqp,
                         const float* Wkvp, const float* bkvp,
                         const float* rot, const float* trans,
                         float* q, float* k, float* v,
                         float* qp, float* kp, float* vp)
{
    __shared__ float sL[2 * CS];      // 8 KB
    __shared__ float rawL[2 * 576];   // 4.5 KB
    __shared__ float Rf[18], Tf[6];
    const int t = threadIdx.x;        // 288
    const int i0 = blockIdx.x * 2;

    // stage 2 s-rows (f32, float4)
    {
        const float4* s4 = (const float4*)(s + i0 * CS);
        float4* sL4 = (float4*)sL;
        for (int vv = t; vv < 512; vv += 288) sL4[vv] = s4[vv];
    }
    if (t < 18) Rf[t] = rot[i0 * 9 + t];
    else if (t >= 32 && t < 38) Tf[t - 32] = trans[i0 * 3 + (t - 32)];
    __syncthreads();

    const int c0 = 4 * t;             // [0,1152)
    const float* W; const float* bv; int c, ldim;
    if (c0 < 192)      { W = Wq;   bv = bq;   c = c0;       ldim = 192; }
    else if (c0 < 576) { W = Wkv;  bv = bkv;  c = c0 - 192; ldim = 384; }
    else if (c0 < 720) { W = Wqp;  bv = bqp;  c = c0 - 576; ldim = 144; }
    else               { W = Wkvp; bv = bkvp; c = c0 - 720; ldim = 432; }

    float acc[2][4];
    #pragma unroll
    for (int u = 0; u < 4; ++u) { float b = bv[c + u]; acc[0][u] = b; acc[1][u] = b; }
    for (int kk = 0; kk < CS; ++kk) {
        float4 wv = *(const float4*)&W[kk * ldim + c];
        float f0 = sL[kk], f1 = sL[CS + kk];
        acc[0][0] += f0 * wv.x; acc[0][1] += f0 * wv.y;
        acc[0][2] += f0 * wv.z; acc[0][3] += f0 * wv.w;
        acc[1][0] += f1 * wv.x; acc[1][1] += f1 * wv.y;
        acc[1][2] += f1 * wv.z; acc[1][3] += f1 * wv.w;
    }

    #pragma unroll
    for (int r = 0; r < 2; ++r) {
        int n = i0 + r;
        if (c0 < 192) {
            #pragma unroll
            for (int u = 0; u < 4; ++u) q[n * 192 + c0 + u] = acc[r][u];
        } else if (c0 < 576) {
            // cc%4==0 block never straddles h (32) or k/v (16) boundaries
            int cc = c0 - 192, h = cc >> 5, t2 = cc & 31;
            if (t2 < 16) {
                #pragma unroll
                for (int u = 0; u < 4; ++u) k[n * 192 + h * 16 + t2 + u] = acc[r][u];
            } else {
                #pragma unroll
                for (int u = 0; u < 4; ++u) v[n * 192 + h * 16 + (t2 - 16) + u] = acc[r][u];
            }
        } else {
            #pragma unroll
            for (int u = 0; u < 4; ++u) rawL[r * 576 + (c0 - 576) + u] = acc[r][u];
        }
    }
    __syncthreads();

    // rotation: rawL[r] = [qp_raw(144: x48|y48|z48) | kvp_raw(432: x144|y144|z144)]
    for (int task = t; task < 384; task += 288) {
        int r = task / 192, p = task % 192;
        const float* raw = rawL + r * 576;
        const float* R = Rf + r * 9;
        const float* T = Tf + r * 3;
        int n = i0 + r;
        float x, y, zc;
        if (p < 48) { x = raw[p];        y = raw[48 + p];   zc = raw[96 + p]; }
        else { int pk = p - 48;
               x = raw[144 + pk]; y = raw[288 + pk]; zc = raw[432 + pk]; }
        float rx = R[0]*x + R[1]*y + R[2]*zc + T[0];
        float ry = R[3]*x + R[4]*y + R[5]*zc + T[1];
        float rz = R[6]*x + R[7]*y + R[8]*zc + T[2];
        if (p < 48) {
            int h = p >> 2, pp = p & 3, b = n * 144 + h * 12 + pp * 3;
            qp[b] = rx; qp[b + 1] = ry; qp[b + 2] = rz;
        } else {
            int pk = p - 48, h = pk / 12, idx = pk % 12;
            if (idx < 4) { int b = n * 144 + h * 12 + idx * 3;
                           kp[b] = rx; kp[b + 1] = ry; kp[b + 2] = rz; }
            else         { int b = n * 288 + h * 24 + (idx - 4) * 3;
                           vp[b] = rx; vp[b + 1] = ry; vp[b + 2] = rz; }
        }
    }
}

// ---------------------------------------------------------------------------
// K2: fused bias + logits + softmax + (o, o_pt, o_pair) per query row i.
// grid 512 x 512. f32 inputs; z via float4; Wb transposed in LDS ([h][c]).
// cat layout: o(0..191) x(192..287) y(288..383) z(384..479) norm(480..575) pair(576..2111)
// ---------------------------------------------------------------------------
__global__ void attn_fused(const float* q, const float* k, const float* v,
                           const float* qp, const float* kp, const float* vp,
                           const float* z, const float* Wb, const float* bb,
                           const float* head_w, const float* mask,
                           const float* rot, const float* trans, float* cat)
{
    __shared__ float attL[H * N];        // 24 KB
    __shared__ float WbT[H * CZ];        // 6 KB, [h][c]
    __shared__ float pairP[4 * H * CZ];  // 24 KB
    __shared__ float qL[192], qpL[144];
    __shared__ float RL[9], TL[3], bbL[H], hwL[H];
    __shared__ float miS;
    int t = threadIdx.x;   // 512
    int i = blockIdx.x;

    for (int idx = t; idx < H * CZ; idx += 512)
        WbT[idx] = Wb[(idx & 127) * H + (idx >> 7)];   // WbT[h*128+c] = Wb[c][h]
    if (t < 192) qL[t] = q[i * 192 + t];
    else if (t < 336) qpL[t - 192] = qp[i * 144 + (t - 192)];
    else if (t < 345) RL[t - 336] = rot[i * 9 + (t - 336)];
    else if (t < 348) TL[t - 345] = trans[i * 3 + (t - 345)];
    else if (t < 360) bbL[t - 348] = bb[t - 348];
    else if (t < 372) {
        float x = head_w[t - 360];
        float sp = (x > 20.f) ? x : log1pf(expf(x));
        hwL[t - 360] = sp * 0.13608276348795434f;   // softplus * sqrt(1/54)
    }
    else if (t == 372) miS = mask[i];
    __syncthreads();

    // ---- Phase B: logits, thread = key index j ----
    {
        int j = t;
        float bj[H];
        #pragma unroll
        for (int h = 0; h < H; ++h) bj[h] = bbL[h];
        const float4* zrow4 = (const float4*)(z + (size_t)(i * N + j) * CZ);
        for (int c4 = 0; c4 < 32; ++c4) {
            float4 zv = zrow4[c4];
            #pragma unroll
            for (int h = 0; h < H; ++h) {
                float4 wv = *(const float4*)&WbT[h * CZ + c4 * 4];
                bj[h] += zv.x * wv.x + zv.y * wv.y + zv.z * wv.z + zv.w * wv.w;
            }
        }
        float mterm = 100000.0f * (miS * mask[j] - 1.0f);
        const float* krow  = k  + j * 192;
        const float* kprow = kp + j * 144;
        #pragma unroll
        for (int h = 0; h < H; ++h) {
            float qk = 0.f;
            #pragma unroll
            for (int dq = 0; dq < 4; ++dq) {
                float4 k4 = *(const float4*)(krow + h * 16 + dq * 4);
                qk += qL[h*16+dq*4+0]*k4.x + qL[h*16+dq*4+1]*k4.y
                    + qL[h*16+dq*4+2]*k4.z + qL[h*16+dq*4+3]*k4.w;
            }
            float pt = 0.f;
            #pragma unroll
            for (int p3 = 0; p3 < 3; ++p3) {
                float4 kp4 = *(const float4*)(kprow + h * 12 + p3 * 4);
                float d0 = qpL[h*12+p3*4+0] - kp4.x;
                float d1 = qpL[h*12+p3*4+1] - kp4.y;
                float d2 = qpL[h*12+p3*4+2] - kp4.z;
                float d3 = qpL[h*12+p3*4+3] - kp4.w;
                pt += d0*d0 + d1*d1 + d2*d2 + d3*d3;
            }
            attL[h * N + j] = qk * 0.14433756729740643f     // sqrt(1/48)
                            + 0.5773502691896258f * bj[h]   // sqrt(1/3)
                            - 0.5f * hwL[h] * pt + mterm;
        }
    }
    __syncthreads();

    // ---- Phase C: softmax per head (one wave per head) ----
    {
        int w = t >> 6, l = t & 63;
        for (int h = w; h < H; h += 8) {
            float av[8];
            #pragma unroll
            for (int kk = 0; kk < 8; ++kk) av[kk] = attL[h * N + kk * 64 + l];
            float m = av[0];
            #pragma unroll
            for (int kk = 1; kk < 8; ++kk) m = fmaxf(m, av[kk]);
            for (int off = 1; off < 64; off <<= 1) m = fmaxf(m, __shfl_xor(m, off));
            float ssum = 0.f;
            #pragma unroll
            for (int kk = 0; kk < 8; ++kk) { av[kk] = __expf(av[kk] - m); ssum += av[kk]; }
            for (int off = 1; off < 64; off <<= 1) ssum += __shfl_xor(ssum, off);
            float inv = 1.0f / ssum;
            #pragma unroll
            for (int kk = 0; kk < 8; ++kk) attL[h * N + kk * 64 + l] = av[kk] * inv;
        }
    }
    __syncthreads();

    // ---- Phase D1: o (192 thr) and o_pt + inverse frame + norm (96 thr) ----
    if (t < 192) {
        int h = t >> 4, d = t & 15;
        float acc = 0.f;
        for (int j = 0; j < N; ++j) acc += attL[h * N + j] * v[j * 192 + h * 16 + d];
        cat[i * 2112 + t] = acc;
    } else if (t < 288) {
        int hp = t - 192, h = hp >> 3, p = hp & 7;
        float ax = 0, ay = 0, az = 0;
        for (int j = 0; j < N; ++j) {
            float a_ = attL[h * N + j];
            int b2 = j * 288 + h * 24 + p * 3;
            ax += a_ * vp[b2]; ay += a_ * vp[b2 + 1]; az += a_ * vp[b2 + 2];
        }
        float gx = ax - TL[0], gy = ay - TL[1], gz = az - TL[2];
        float lx = RL[0]*gx + RL[3]*gy + RL[6]*gz;   // R^T
        float ly = RL[1]*gx + RL[4]*gy + RL[7]*gz;
        float lz = RL[2]*gx + RL[5]*gy + RL[8]*gz;
        float nrm = sqrtf(lx*lx + ly*ly + lz*lz + 1e-8f);
        cat[i * 2112 + 192 + hp] = lx;
        cat[i * 2112 + 288 + hp] = ly;
        cat[i * 2112 + 384 + hp] = lz;
        cat[i * 2112 + 480 + hp] = nrm;
    }

    // ---- Phase D2: o_pair = a @ z[i] (4 j-quarters x 128 c) ----
    {
        int quarter = t >> 7, c = t & 127;
        float pacc[H];
        #pragma unroll
        for (int h = 0; h < H; ++h) pacc[h] = 0.f;
        int j0 = quarter * 128;
        for (int j = j0; j < j0 + 128; ++j) {
            float zc = z[(size_t)(i * N + j) * CZ + c];
            #pragma unroll
            for (int h = 0; h < H; ++h) pacc[h] += attL[h * N + j] * zc;
        }
        #pragma unroll
        for (int h = 0; h < H; ++h) pairP[quarter * (H * CZ) + h * CZ + c] = pacc[h];
    }
    __syncthreads();
    for (int idx = t; idx < H * CZ; idx += 512)
        cat[i * 2112 + 576 + idx] =
            pairP[idx] + pairP[1536 + idx] + pairP[3072 + idx] + pairP[4608 + idx];
}

// ---------------------------------------------------------------------------
// K3: out = cat @ Wout + bout (512x2112 @ 2112x1024), tiled.
// grid (4 col-tiles, 32 row-tiles) x 256 thr. Tile 16 rows x 256 cols;
// thread owns 4 rows x 4 cols. K-chunks of 64 staged in LDS.
// ---------------------------------------------------------------------------
__global__ void final_gemm(const float* cat, const float* Wout, const float* bout,
                           float* out)
{
    __shared__ float catL[16 * 64];   // 4 KB
    const int t = threadIdx.x;        // 256
    const int tc = t & 63, tr = t >> 6;          // col-group [0,64), row-group [0,4)
    const int i0 = blockIdx.y * 16;
    const int c0 = blockIdx.x * 256 + tc * 4;

    float acc[4][4];
    #pragma unroll
    for (int u = 0; u < 4; ++u) {
        float b = bout[c0 + u];
        #pragma unroll
        for (int r = 0; r < 4; ++r) acc[r][u] = b;
    }

    for (int k0 = 0; k0 < 2112; k0 += 64) {
        for (int vv = t; vv < 1024; vv += 256) {
            int r = vv >> 6, kk = vv & 63;
            catL[r * 64 + kk] = cat[(i0 + r) * 2112 + k0 + kk];
        }
        __syncthreads();
        for (int kk = 0; kk < 64; ++kk) {
            float4 wv = *(const float4*)&Wout[(size_t)(k0 + kk) * 1024 + c0];
            #pragma unroll
            for (int r = 0; r < 4; ++r) {
                float f = catL[(tr * 4 + r) * 64 + kk];   // wave-uniform row -> broadcast
                acc[r][0] += f * wv.x; acc[r][1] += f * wv.y;
                acc[r][2] += f * wv.z; acc[r][3] += f * wv.w;
            }
        }
        __syncthreads();
    }

    #pragma unroll
    for (int r = 0; r < 4; ++r) {
        float4 o4 = make_float4(acc[r][0], acc[r][1], acc[r][2], acc[r][3]);
        *(float4*)&out[(size_t)(i0 + tr * 4 + r) * 1024 + c0] = o4;
    }
}

extern "C" void kernel_launch(void* const* d_in, const int* in_sizes, int n_in,
                              void* d_out, int out_size, void* d_ws, size_t ws_size,
                              hipStream_t stream)
{
    const float* s      = (const float*)d_in[0];
    const float* z      = (const float*)d_in[1];
    const float* rot    = (const float*)d_in[2];
    const float* trans  = (const float*)d_in[3];
    const float* mask   = (const float*)d_in[4];
    const float* Wq     = (const float*)d_in[5];  const float* bq   = (const float*)d_in[6];
    const float* Wkv    = (const float*)d_in[7];  const float* bkv  = (const float*)d_in[8];
    const float* Wqp    = (const float*)d_in[9];  const float* bqp  = (const float*)d_in[10];
    const float* Wkvp   = (const float*)d_in[11]; const float* bkvp = (const float*)d_in[12];
    const float* Wb     = (const float*)d_in[13]; const float* bb   = (const float*)d_in[14];
    const float* head_w = (const float*)d_in[15];
    const float* Wout   = (const float*)d_in[16]; const float* bout = (const float*)d_in[17];

    float* w   = (float*)d_ws;          // 6.4 MB total
    float* q   = w;                     // 512*192
    float* k   = q  + 98304;
    float* v   = k  + 98304;
    float* qp  = v  + 98304;            // 512*144
    float* kp  = qp + 73728;
    float* vp  = kp + 73728;            // 512*288
    float* cat = vp + 147456;           // 512*2112
    (void)ws_size; (void)in_sizes; (void)n_in; (void)out_size;

    proj_all  <<<256, 288, 0, stream>>>(s, Wq, bq, Wkv, bkv, Wqp, bqp, Wkvp, bkvp,
                                        rot, trans, q, k, v, qp, kp, vp);
    attn_fused<<<512, 512, 0, stream>>>(q, k, v, qp, kp, vp, z, Wb, bb, head_w, mask,
                                        rot, trans, cat);
    final_gemm<<<dim3(4, 32), 256, 0, stream>>>(cat, Wout, bout, (float*)d_out);
}